// Round 11
// baseline (302.019 us; speedup 1.0000x reference)
//
#include <hip/hip_runtime.h>

#define PPX  128
#define PP2  16384
#define IMH  896
#define IMW  896
#define NB   24
#define NI   8
#define HP   1152
#define WP   1152
#define MAXG 6              // scheduled levels 0..MAXG-1; lvl>=MAXG -> fallback
#define NMB  (NI*NB*8)      // 1536 mask blocks (8 chunks per box)
#define NCPY1 3072          // copy blocks at the FRONT of step1's grid
#define M1    12            // crop member slots in step1

// ws layout (float units):
// [0..5]                      mu_p[3], sd_p[3]
// [8 .. 8+192*8)              per-box structs
// [2048 .. +192*512)          mask bitmaps (uint32)
// [100352 .. +8*32)           schedule: per image lvl[24] + cnt[MAXG] at [24..] (uint32)
// [100608 .. +8*6*24)         member lists [img][lvl][24] (uint32)
// [101760 .. +192*8)          mask-sum partials [box][chunk]
// [103424 .. +8*24*32*6)      partial stats [box][blk][6]
// [140288 .. +8*24*PP2*3)     pbg slot per box (~38 MB)
#define WS_BOX  8
#define WS_MASK 2048
#define WS_SCH  100352
#define WS_LIST 100608
#define WS_MSUM 101760
#define WS_PART 103424
#define WS_PBG  140288

__device__ __forceinline__ void box_geom(const float* __restrict__ bx,
    const float* __restrict__ Wsc, const float* __restrict__ bsc,
    float& scale, float& ps, int& yi, int& xi, int& ph, int& vld)
{
  float ya=bx[0], xa=bx[1], yb=bx[2], xb=bx[3];
  float bh=(yb-ya)/(float)IMH, bw=(xb-xa)/(float)IMW;
  float z = bh*Wsc[0]+bw*Wsc[1]+bsc[0];
  float sig = 1.f/(1.f+expf(-z));
  scale = sig*0.4f;
  float h=yb-ya, w=xb-xa;
  ps = floorf(sqrtf((h*w)*scale));
  float oy=ya+h*0.5f, ox=xa+w*0.5f;
  float ymp=fmaxf(oy-ps*0.5f,0.f), xmp=fmaxf(ox-ps*0.5f,0.f);
  if (ymp+ps>(float)IMH) ymp=(float)IMH-ps;
  if (xmp+ps>(float)IMW) xmp=(float)IMW-ps;
  yi=(int)ymp; xi=(int)xmp; ph=(int)ps;
  vld = (ps>60.f) ? 1 : 0;
}

// paste value at region-relative (rr,cc); expressions identical to prior passing rounds.
__device__ __forceinline__ void analytic3(int rr, int cc, float phf,
    const float* __restrict__ pbg1, const float* __restrict__ patch,
    const unsigned* msk, const float* ab, float v[3])
{
  float sy = ((rr + 0.5f)*128.0f)/phf - 0.5f;
  float sx = ((cc + 0.5f)*128.0f)/phf - 0.5f;
  sy = fminf(fmaxf(sy, 0.f), 127.f);
  sx = fminf(fmaxf(sx, 0.f), 127.f);
  float fy0 = floorf(sy), fx0 = floorf(sx);
  int py0 = (int)fy0, px0 = (int)fx0;
  int py1 = py0 + 1 < 127 ? py0 + 1 : 127;
  int px1 = px0 + 1 < 127 ? px0 + 1 : 127;
  float wy = sy - fy0, wx = sx - fx0;
  int i00 = (py0<<7)+px0, i01 = (py0<<7)+px1, i10 = (py1<<7)+px0, i11 = (py1<<7)+px1;
  bool m00 = (msk[i00>>5] >> (i00&31)) & 1u;
  bool m01 = (msk[i01>>5] >> (i01&31)) & 1u;
  bool m10 = (msk[i10>>5] >> (i10&31)) & 1u;
  bool m11 = (msk[i11>>5] >> (i11&31)) & 1u;
  #pragma unroll
  for (int ch = 0; ch < 3; ++ch) {
    float a = ab[ch], be = ab[3+ch];
    float t00 = m00 ? patch[i00*3+ch]*a + be : pbg1[i00*3+ch];
    float t01 = m01 ? patch[i01*3+ch]*a + be : pbg1[i01*3+ch];
    float t10 = m10 ? patch[i10*3+ch]*a + be : pbg1[i10*3+ch];
    float t11 = m11 ? patch[i11*3+ch]*a + be : pbg1[i11*3+ch];
    v[ch] = (1.f-wy)*((1.f-wx)*t00 + wx*t01) + wy*((1.f-wx)*t10 + wx*t11);
  }
}

// plain crop (no read-through): box n of image b, crop block `blk` (512 px), src given.
__device__ __forceinline__ void crop_plain(
    const float* __restrict__ src, float* __restrict__ ws, int b, int n, int blk,
    float (*s_red)[6])
{
  const int tid = threadIdx.x;
  const int* bi = (const int*)(ws + WS_BOX + (b*NB + n)*8);
  const int yi = bi[2], xi = bi[3], ph = bi[4];
  const float phf = (float)(ph > 1 ? ph : 1);
  float* __restrict__ pbg = ws + WS_PBG + (size_t)(b*NB + n)*PP2*3;
  float sm[3] = {0,0,0}, sq[3] = {0,0,0};
  #pragma unroll
  for (int k = 0; k < 2; ++k) {
    int idx = blk*512 + k*256 + tid;
    int py = idx >> 7, px = idx & 127;
    float ys = ((float)yi + (py + 0.5f)*phf*(1.0f/PPX)) - 0.5f;
    float xs = ((float)xi + (px + 0.5f)*phf*(1.0f/PPX)) - 0.5f;
    ys = fminf(fmaxf(ys, 0.f), (float)(HP-1));
    xs = fminf(fmaxf(xs, 0.f), (float)(WP-1));
    float fy0 = floorf(ys), fx0 = floorf(xs);
    int y0 = (int)fy0, x0 = (int)fx0;
    int y1 = y0 + 1 < HP-1 ? y0 + 1 : HP-1;
    int x1 = x0 + 1 < WP-1 ? x0 + 1 : WP-1;
    float wy = ys - fy0, wx = xs - fx0;
    bool y0i = y0 < IMH, y1i = y1 < IMH, x0i = x0 < IMW, x1i = x1 < IMW;
    const float* r0 = src + (size_t)y0*IMW*3;
    const float* r1 = src + (size_t)y1*IMW*3;
    #pragma unroll
    for (int c = 0; c < 3; ++c) {
      float v00 = (y0i && x0i) ? r0[x0*3+c] : 0.f;
      float v01 = (y0i && x1i) ? r0[x1*3+c] : 0.f;
      float v10 = (y1i && x0i) ? r1[x0*3+c] : 0.f;
      float v11 = (y1i && x1i) ? r1[x1*3+c] : 0.f;
      float v = (1.f-wy)*((1.f-wx)*v00 + wx*v01) + wy*((1.f-wx)*v10 + wx*v11);
      pbg[idx*3+c] = v;
      sm[c] += v; sq[c] += v*v;
    }
  }
  float vals[6] = {sm[0],sm[1],sm[2],sq[0],sq[1],sq[2]};
  #pragma unroll
  for (int off = 32; off; off >>= 1)
    #pragma unroll
    for (int k = 0; k < 6; ++k) vals[k] += __shfl_down(vals[k], off);
  int wid = tid >> 6;
  __syncthreads();
  if ((tid & 63) == 0)
    for (int k = 0; k < 6; ++k) s_red[wid][k] = vals[k];
  __syncthreads();
  if (tid == 0) {
    float* part = ws + WS_PART + (size_t)((b*NB + n)*32 + blk)*6;
    for (int k = 0; k < 6; ++k)
      part[k] = s_red[0][k] + s_red[1][k] + s_red[2][k] + s_red[3][k];
  }
}

// ------------- setup: masks (1536 blks) + sched/patch-stats (1 blk) -------------
__global__ __launch_bounds__(256) void setup_k(
    const float* __restrict__ boxes,
    const float* __restrict__ Wsc, const float* __restrict__ bsc,
    const float* __restrict__ Wg, const float* __restrict__ bgv,
    const float* __restrict__ patch, float* __restrict__ ws)
{
  const int bid = blockIdx.x, tid = threadIdx.x;

  if (bid < NMB) {
    // ---- mask chunk q of box bn ----
    const int bn = bid >> 3, q = bid & 7;
    float scale, ps; int yi, xi, ph, vld;
    box_geom(boxes + bn*4, Wsc, bsc, scale, ps, yi, xi, ph, vld);
    if (q == 0 && tid == 0) {
      float* bst = ws + WS_BOX + bn*8;
      bst[0] = scale;
      bst[1] = ps;
      ((int*)bst)[2] = yi;
      ((int*)bst)[3] = xi;
      ((int*)bst)[4] = ph;
      bst[5] = vld ? 1.f : 0.f;
    }
    float bh = (boxes[bn*4+2]-boxes[bn*4+0])/(float)IMH;
    float bw = (boxes[bn*4+3]-boxes[bn*4+1])/(float)IMW;
    unsigned* mwords = ((unsigned*)ws) + WS_MASK + bn*512;
    float lsum = 0.f;
    const int lane = tid & 63;
    #pragma unroll
    for (int i = 0; i < 8; ++i) {
      int p = q*2048 + i*256 + tid;
      float zz = bh*Wg[p] + bw*Wg[PP2 + p] + bgv[p];
      lsum += 1.0f / (1.0f + expf(-zz));
      unsigned long long m = __ballot(zz > 0.0f);
      if (lane == 0) {
        int base = p >> 5;
        mwords[base]   = (unsigned)(m & 0xffffffffULL);
        mwords[base+1] = (unsigned)(m >> 32);
      }
    }
    #pragma unroll
    for (int off = 32; off; off >>= 1) lsum += __shfl_down(lsum, off);
    __shared__ float s_r[4];
    if ((tid & 63) == 0) s_r[tid >> 6] = lsum;
    __syncthreads();
    if (tid == 0) ws[WS_MSUM + bn*8 + q] = s_r[0] + s_r[1] + s_r[2] + s_r[3];
    return;
  }

  // ---- last block: patch stats + level schedule + member lists ----
  __shared__ float s_red6[256][6];
  {
    float s0=0,s1=0,s2=0,q0=0,q1=0,q2=0;
    for (int i = tid; i < PP2; i += 256) {
      float a = patch[i*3+0], b = patch[i*3+1], c = patch[i*3+2];
      s0+=a; s1+=b; s2+=c; q0+=a*a; q1+=b*b; q2+=c*c;
    }
    s_red6[tid][0]=s0; s_red6[tid][1]=s1; s_red6[tid][2]=s2;
    s_red6[tid][3]=q0; s_red6[tid][4]=q1; s_red6[tid][5]=q2;
    __syncthreads();
    for (int s = 128; s > 0; s >>= 1) {
      if (tid < s)
        for (int k=0;k<6;++k) s_red6[tid][k] += s_red6[tid+s][k];
      __syncthreads();
    }
    if (tid == 0) {
      for (int c=0;c<3;++c) {
        float mu  = s_red6[0][c]   * (1.0f/PP2);
        float var = s_red6[0][3+c] * (1.0f/PP2) - mu*mu;
        float sd  = sqrtf(fmaxf(var, 0.f)) + 1e-6f;
        ws[c] = mu; ws[3+c] = sd;
      }
    }
  }
  __syncthreads();
  __shared__ int g_yi[NI*NB], g_xi[NI*NB], g_ph[NI*NB], g_vl[NI*NB];
  if (tid < NI*NB) {
    float scale, ps; int yi, xi, ph, vld;
    box_geom(boxes + tid*4, Wsc, bsc, scale, ps, yi, xi, ph, vld);
    g_yi[tid]=yi; g_xi[tid]=xi; g_ph[tid]=ph; g_vl[tid]=vld;
  }
  __syncthreads();
  if (tid < NI) {
    unsigned* sch = ((unsigned*)ws) + WS_SCH + tid*32;
    unsigned* lst = ((unsigned*)ws) + WS_LIST + tid*(MAXG*NB);
    int lv[NB];
    int cnt[MAXG];
    for (int L = 0; L < MAXG; ++L) cnt[L] = 0;
    for (int n = 0; n < NB; ++n) {
      int idx = tid*NB + n;
      if (!g_vl[idx]) { lv[n] = -1; sch[n] = 255u; continue; }
      int y0 = g_yi[idx]-2, y1 = g_yi[idx]+g_ph[idx]+3;
      int x0 = g_xi[idx]-2, x1 = g_xi[idx]+g_ph[idx]+3;
      int L = 0;
      for (int m = 0; m < n; ++m) {
        if (lv[m] < 0) continue;
        int mi = tid*NB + m;
        int my0 = g_yi[mi]-2, my1 = g_yi[mi]+g_ph[mi]+3;
        int mx0 = g_xi[mi]-2, mx1 = g_xi[mi]+g_ph[mi]+3;
        if (y0 < my1 && my0 < y1 && x0 < mx1 && mx0 < x1)
          L = max(L, lv[m] + 1);
      }
      lv[n] = L;
      sch[n] = (unsigned)L;
      if (L < MAXG) lst[L*NB + cnt[L]++] = (unsigned)n;
    }
    for (int L = 0; L < MAXG; ++L) sch[24 + L] = (unsigned)cnt[L];
  }
}

// ------------- step1: [copy 3072][crop lvl0 3072][loss 1] -------------
__global__ __launch_bounds__(256) void step1_k(
    float* __restrict__ out, const float* __restrict__ images,
    float* __restrict__ ws)
{
  const int bid = blockIdx.x, tid = threadIdx.x;
  if (bid < NCPY1) {
    // ---- image copy at the front of the grid ----
    const float4* src4 = (const float4*)images;
    float4* dst4 = (float4*)out;
    const int n4 = NI*IMH*IMW*3/4;
    for (int i = bid*256 + tid; i < n4; i += NCPY1*256) dst4[i] = src4[i];
    return;
  }
  if (bid == NCPY1 + NI*M1*32) {
    // ---- scalar loss ----
    if (tid == 0) {
      float total = 0.f;
      for (int b = 0; b < NI; ++b) {
        float sum_s = 0.f, cnt = 0.f, bgl = 0.f;
        for (int n = 0; n < NB; ++n) {
          const float* bst = ws + WS_BOX + (b*NB + n)*8;
          float v = bst[5];
          float msum = 0.f;
          for (int q = 0; q < 8; ++q) msum += ws[WS_MSUM + (b*NB + n)*8 + q];
          sum_s += bst[0]*v; cnt += v; bgl += (msum*(1.0f/PP2))*v;
        }
        float nn = fmaxf(cnt, 1.0f);
        float m = sum_s / nn;
        float var = 0.f;
        for (int n = 0; n < NB; ++n) {
          const float* bst = ws + WS_BOX + (b*NB + n)*8;
          float d = bst[0] - m;
          var += bst[5]*d*d;
        }
        var /= nn;
        total += bgl + m + 0.5f*var;
      }
      out[(size_t)NI*IMH*IMW*3] = total;
    }
    return;
  }
  // ---- crop level 0 from `images` ----
  const int w = bid - NCPY1;
  const int b = w / (M1*32);
  const int rem = w - b*(M1*32);
  const int j = rem >> 5, blk = rem & 31;
  __shared__ float s_red[4][6];
  __shared__ int s_cn[NB];
  __shared__ int s_cc;
  const unsigned* sch = ((const unsigned*)ws) + WS_SCH + b*32;
  if (tid == 0) s_cc = (int)sch[24 + 0];
  __syncthreads();
  const int cc = s_cc;
  if (j >= cc) return;
  if (tid < cc) s_cn[tid] = (int)(((const unsigned*)ws) + WS_LIST + b*(MAXG*NB))[0*NB + tid];
  __syncthreads();
  const float* src = images + (size_t)b*IMH*IMW*3;
  for (int jj = j; jj < cc; jj += M1)
    crop_plain(src, ws, b, s_cn[jj], blk, s_red);
}

// ------------- step s (2..7): paste(level s-2) || crop(level s-1), M slots -------------
__global__ __launch_bounds__(256) void step_k(
    float* __restrict__ out, const float* __restrict__ patch,
    float* __restrict__ ws, int s, int M)
{
  const int bid = blockIdx.x, tid = threadIdx.x;
  const int b = bid / (M*64);
  const int rem = bid - b*(M*64);
  const int j = rem >> 6;          // member slot
  const int r = rem & 63;          // 0..31 paste chunk, 32..63 crop block
  const int gc = s - 1, gp = s - 2;

  __shared__ int s_cc, s_cp;
  __shared__ int s_pn[NB], s_pyi[NB], s_pxi[NB], s_pph[NB];
  __shared__ int s_cn[NB];
  __shared__ float s_abp[NB][6];
  __shared__ unsigned s_mask[512];
  __shared__ float s_red[4][6];

  const unsigned* sch = ((const unsigned*)ws) + WS_SCH + b*32;
  if (tid == 0) {
    s_cc = (gc < MAXG) ? (int)sch[24 + gc] : 0;
    s_cp = (int)sch[24 + gp];
  }
  __syncthreads();
  const int cc = s_cc, cp = s_cp;
  if (j >= cc && j >= cp) return;

  const unsigned* lst = ((const unsigned*)ws) + WS_LIST + b*(MAXG*NB);
  if (tid < cp) {
    int n = (int)lst[gp*NB + tid];
    s_pn[tid] = n;
    const int* bi = (const int*)(ws + WS_BOX + (b*NB + n)*8);
    s_pyi[tid] = bi[2]; s_pxi[tid] = bi[3]; s_pph[tid] = bi[4];
  }
  if (tid >= 32 && tid - 32 < cc)
    s_cn[tid - 32] = (int)lst[gc*NB + (tid - 32)];
  __syncthreads();

  // alpha/beta for all gp members, 8 members in parallel
  for (int jm = (tid >> 5); jm < cp; jm += 8) {
    const int lane = tid & 31;
    const float* part = ws + WS_PART + (size_t)((b*NB + s_pn[jm])*32 + lane)*6;
    float v[6];
    #pragma unroll
    for (int k = 0; k < 6; ++k) v[k] = part[k];
    #pragma unroll
    for (int off = 16; off; off >>= 1)
      #pragma unroll
      for (int k = 0; k < 6; ++k) v[k] += __shfl_down(v[k], off, 32);
    if (lane == 0) {
      #pragma unroll
      for (int c = 0; c < 3; ++c) {
        float mu  = v[c]   * (1.0f/PP2);
        float var = v[3+c] * (1.0f/PP2) - mu*mu;
        float sd  = sqrtf(fmaxf(var, 0.f)) + 1e-6f;
        float alpha = sd / ws[3+c];
        s_abp[jm][c]   = alpha;
        s_abp[jm][3+c] = mu - ws[c]*alpha;
      }
    }
  }
  __syncthreads();

  float* __restrict__ img = out + (size_t)b*IMH*IMW*3;

  if (r < 32) {
    // ---- paste chunk r of members j, j+M, ... of level gp ----
    for (int jj = j; jj < cp; jj += M) {
      const int n = s_pn[jj];
      {
        const unsigned* mwords = ((const unsigned*)ws) + WS_MASK + (b*NB + n)*512;
        s_mask[tid]       = mwords[tid];
        s_mask[tid + 256] = mwords[tid + 256];
      }
      __syncthreads();
      const int yi = s_pyi[jj], xi = s_pxi[jj], ph = s_pph[jj];
      const float phf = (float)(ph > 1 ? ph : 1);
      const float* pbgp = ws + WS_PBG + (size_t)(b*NB + n)*PP2*3;
      const int tot = ph*ph;
      const int chunk = (tot + 31) / 32;
      const int i0 = r*chunk;
      const int i1 = min(tot, i0 + chunk);
      for (int idx = i0 + tid; idx < i1; idx += 256) {
        int rr = (int)((unsigned)idx / (unsigned)ph);
        int cx = idx - rr*ph;
        float v[3];
        analytic3(rr, cx, phf, pbgp, patch, s_mask, &s_abp[jj][0], v);
        float* dst = img + ((size_t)(yi + rr)*IMW + (xi + cx))*3;
        dst[0] = v[0]; dst[1] = v[1]; dst[2] = v[2];
      }
      __syncthreads();
    }
    return;
  }

  // ---- crop block (r-32) of members j, j+M, ... of level gc (read-through gp) ----
  const int blk = r - 32;
  for (int jj = j; jj < cc; jj += M) {
    const int n = s_cn[jj];
    const int* bi = (const int*)(ws + WS_BOX + (b*NB + n)*8);
    const int yi = bi[2], xi = bi[3], ph = bi[4];
    const float phf = (float)(ph > 1 ? ph : 1);
    float* __restrict__ pbg = ws + WS_PBG + (size_t)(b*NB + n)*PP2*3;

    float sm[3] = {0,0,0}, sq[3] = {0,0,0};
    #pragma unroll
    for (int k = 0; k < 2; ++k) {
      int idx = blk*512 + k*256 + tid;
      int py = idx >> 7, px = idx & 127;
      float ys = ((float)yi + (py + 0.5f)*phf*(1.0f/PPX)) - 0.5f;
      float xs = ((float)xi + (px + 0.5f)*phf*(1.0f/PPX)) - 0.5f;
      ys = fminf(fmaxf(ys, 0.f), (float)(HP-1));
      xs = fminf(fmaxf(xs, 0.f), (float)(WP-1));
      float fy0 = floorf(ys), fx0 = floorf(xs);
      int y0 = (int)fy0, x0 = (int)fx0;
      int y1 = y0 + 1 < HP-1 ? y0 + 1 : HP-1;
      int x1 = x0 + 1 < WP-1 ? x0 + 1 : WP-1;
      float wy = ys - fy0, wx = xs - fx0;
      float cn[4][3];
      int Ys[2] = {y0, y1}, Xs[2] = {x0, x1};
      #pragma unroll
      for (int cy = 0; cy < 2; ++cy) {
        #pragma unroll
        for (int cx2 = 0; cx2 < 2; ++cx2) {
          float* v = cn[cy*2+cx2];
          int Y = Ys[cy], X = Xs[cx2];
          if (Y >= IMH || X >= IMW) { v[0]=0.f; v[1]=0.f; v[2]=0.f; continue; }
          int hit = -1;
          for (int p = 0; p < cp; ++p)
            if ((unsigned)(Y - s_pyi[p]) < (unsigned)s_pph[p] &&
                (unsigned)(X - s_pxi[p]) < (unsigned)s_pph[p]) { hit = p; break; }
          if (hit >= 0) {
            const int nph = s_pn[hit];
            const float phfp = (float)(s_pph[hit] > 1 ? s_pph[hit] : 1);
            const unsigned* mw = ((const unsigned*)ws) + WS_MASK + (b*NB + nph)*512;
            const float* pbgp = ws + WS_PBG + (size_t)(b*NB + nph)*PP2*3;
            analytic3(Y - s_pyi[hit], X - s_pxi[hit], phfp, pbgp, patch, mw, &s_abp[hit][0], v);
          } else {
            const float* p = img + ((size_t)Y*IMW + X)*3;
            v[0]=p[0]; v[1]=p[1]; v[2]=p[2];
          }
        }
      }
      #pragma unroll
      for (int c = 0; c < 3; ++c) {
        float v = (1.f-wy)*((1.f-wx)*cn[0][c] + wx*cn[1][c]) + wy*((1.f-wx)*cn[2][c] + wx*cn[3][c]);
        pbg[idx*3+c] = v;
        sm[c] += v; sq[c] += v*v;
      }
    }
    float vals[6] = {sm[0],sm[1],sm[2],sq[0],sq[1],sq[2]};
    #pragma unroll
    for (int off = 32; off; off >>= 1)
      #pragma unroll
      for (int k = 0; k < 6; ++k) vals[k] += __shfl_down(vals[k], off);
    int wid = tid >> 6;
    __syncthreads();
    if ((tid & 63) == 0)
      for (int k = 0; k < 6; ++k) s_red[wid][k] = vals[k];
    __syncthreads();
    if (tid == 0) {
      float* part = ws + WS_PART + (size_t)((b*NB + n)*32 + blk)*6;
      for (int k = 0; k < 6; ++k)
        part[k] = s_red[0][k] + s_red[1][k] + s_red[2][k] + s_red[3][k];
    }
  }
}

// ------------- fallback: serial per-image processing of lvl>=MAXG boxes -------------
__global__ __launch_bounds__(256) void fallback_k(
    float* __restrict__ out, const float* __restrict__ patch, float* __restrict__ ws)
{
  const int b = blockIdx.x, tid = threadIdx.x;
  const unsigned* sch = ((const unsigned*)ws) + WS_SCH + b*32;
  float* __restrict__ img = out + (size_t)b*IMH*IMW*3;
  float* __restrict__ pbg = ws + WS_PBG + (size_t)(b*NB + 0)*PP2*3;
  __shared__ float s_red6[256][6];
  __shared__ float s_ab[6];
  __shared__ unsigned s_mask[512];

  for (int n = 0; n < NB; ++n) {
    unsigned g = sch[n];
    if (g < (unsigned)MAXG || g == 255u) continue;
    const float* bst = ws + WS_BOX + (b*NB + n)*8;
    const int yi = ((const int*)bst)[2];
    const int xi = ((const int*)bst)[3];
    const int ph = ((const int*)bst)[4];
    const float phf = (float)(ph > 1 ? ph : 1);

    float sm[3]={0,0,0}, sq[3]={0,0,0};
    for (int k = 0; k < PP2/256; ++k) {
      int idx = k*256 + tid;
      int py = idx >> 7, px = idx & 127;
      float ys = ((float)yi + (py + 0.5f)*phf*(1.0f/PPX)) - 0.5f;
      float xs = ((float)xi + (px + 0.5f)*phf*(1.0f/PPX)) - 0.5f;
      ys = fminf(fmaxf(ys, 0.f), (float)(HP-1));
      xs = fminf(fmaxf(xs, 0.f), (float)(WP-1));
      float fy0 = floorf(ys), fx0 = floorf(xs);
      int y0 = (int)fy0, x0 = (int)fx0;
      int y1 = y0 + 1 < HP-1 ? y0 + 1 : HP-1;
      int x1 = x0 + 1 < WP-1 ? x0 + 1 : WP-1;
      float wy = ys - fy0, wx = xs - fx0;
      bool y0i = y0 < IMH, y1i = y1 < IMH, x0i = x0 < IMW, x1i = x1 < IMW;
      const float* r0 = img + (size_t)y0*IMW*3;
      const float* r1 = img + (size_t)y1*IMW*3;
      #pragma unroll
      for (int c = 0; c < 3; ++c) {
        float v00 = (y0i && x0i) ? r0[x0*3+c] : 0.f;
        float v01 = (y0i && x1i) ? r0[x1*3+c] : 0.f;
        float v10 = (y1i && x0i) ? r1[x0*3+c] : 0.f;
        float v11 = (y1i && x1i) ? r1[x1*3+c] : 0.f;
        float v = (1.f-wy)*((1.f-wx)*v00 + wx*v01) + wy*((1.f-wx)*v10 + wx*v11);
        pbg[idx*3+c] = v;
        sm[c] += v; sq[c] += v*v;
      }
    }
    s_red6[tid][0]=sm[0]; s_red6[tid][1]=sm[1]; s_red6[tid][2]=sm[2];
    s_red6[tid][3]=sq[0]; s_red6[tid][4]=sq[1]; s_red6[tid][5]=sq[2];
    __syncthreads();
    for (int s2 = 128; s2 > 0; s2 >>= 1) {
      if (tid < s2)
        for (int k=0;k<6;++k) s_red6[tid][k] += s_red6[tid+s2][k];
      __syncthreads();
    }
    if (tid == 0) {
      for (int c=0;c<3;++c) {
        float mu  = s_red6[0][c]   * (1.0f/PP2);
        float var = s_red6[0][3+c] * (1.0f/PP2) - mu*mu;
        float sd  = sqrtf(fmaxf(var, 0.f)) + 1e-6f;
        float alpha = sd / ws[3+c];
        s_ab[c]   = alpha;
        s_ab[3+c] = mu - ws[c]*alpha;
      }
    }
    {
      const unsigned* mwords = ((const unsigned*)ws) + WS_MASK + (b*NB + n)*512;
      s_mask[tid]       = mwords[tid];
      s_mask[tid + 256] = mwords[tid + 256];
    }
    __syncthreads();
    const int tot = ph*ph;
    for (int idx = tid; idx < tot; idx += 256) {
      int rr = (int)((unsigned)idx / (unsigned)ph);
      int cc = idx - rr*ph;
      float v[3];
      analytic3(rr, cc, phf, pbg, patch, s_mask, s_ab, v);
      float* dst = img + ((size_t)(yi + rr)*IMW + (xi + cc))*3;
      dst[0] = v[0]; dst[1] = v[1]; dst[2] = v[2];
    }
    __syncthreads();
  }
}

extern "C" void kernel_launch(void* const* d_in, const int* in_sizes, int n_in,
                              void* d_out, int out_size, void* d_ws, size_t ws_size,
                              hipStream_t stream) {
  const float* boxes  = (const float*)d_in[0];
  const float* images = (const float*)d_in[1];
  const float* patch  = (const float*)d_in[2];
  const float* Wsc    = (const float*)d_in[3];
  const float* bsc    = (const float*)d_in[4];
  const float* Wg     = (const float*)d_in[5];
  const float* bgv    = (const float*)d_in[6];
  float* out = (float*)d_out;
  float* ws  = (float*)d_ws;

  setup_k<<<NMB + 1, 256, 0, stream>>>(boxes, Wsc, bsc, Wg, bgv, patch, ws);
  step1_k<<<NCPY1 + NI*M1*32 + 1, 256, 0, stream>>>(out, images, ws);
  step_k<<<NI*8*64, 256, 0, stream>>>(out, patch, ws, 2, 8);
  step_k<<<NI*4*64, 256, 0, stream>>>(out, patch, ws, 3, 4);
  step_k<<<NI*2*64, 256, 0, stream>>>(out, patch, ws, 4, 2);
  step_k<<<NI*1*64, 256, 0, stream>>>(out, patch, ws, 5, 1);
  step_k<<<NI*1*64, 256, 0, stream>>>(out, patch, ws, 6, 1);
  step_k<<<NI*1*64, 256, 0, stream>>>(out, patch, ws, 7, 1);
  fallback_k<<<NI, 256, 0, stream>>>(out, patch, ws);
}

// Round 12
// 219.653 us; speedup vs baseline: 1.3750x; 1.3750x over previous
//
#include <hip/hip_runtime.h>

#define PPX  128
#define PP2  16384
#define IMH  896
#define IMW  896
#define NB   24
#define NI   8
#define HP   1152
#define WP   1152
#define MAXG 6              // scheduled levels 0..5; lvl>=MAXG -> fallback
#define NMB  (NI*NB*8)      // 1536 mask blocks
#define NCPY 2048           // copy blocks at FRONT of first_k
#define M1   12             // crop slots in first_k

// ws layout (float units):
// [0..5]                      mu_p[3], sd_p[3]
// [8 .. 8+192*8)              per-box structs
// [2048 .. +192*512)          mask bitmaps (uint32)
// [100352 .. +8*32)           schedule: per image lvl[24] + cnt[MAXG] at [24..] (uint32)
// [100608 .. +8*6*24)         member lists [img][lvl][24] (uint32)
// [101760 .. +192*8)          mask-sum partials [box][chunk]
// [103424 .. +8*24*32*6)      partial stats [box][blk][6]
// [140288 .. +8*24*PP2*3)     pbg slot per box (~38 MB)
#define WS_BOX  8
#define WS_MASK 2048
#define WS_SCH  100352
#define WS_LIST 100608
#define WS_MSUM 101760
#define WS_PART 103424
#define WS_PBG  140288

__device__ __forceinline__ void box_geom(const float* __restrict__ bx,
    const float* __restrict__ Wsc, const float* __restrict__ bsc,
    float& scale, float& ps, int& yi, int& xi, int& ph, int& vld)
{
  float ya=bx[0], xa=bx[1], yb=bx[2], xb=bx[3];
  float bh=(yb-ya)/(float)IMH, bw=(xb-xa)/(float)IMW;
  float z = bh*Wsc[0]+bw*Wsc[1]+bsc[0];
  float sig = 1.f/(1.f+expf(-z));
  scale = sig*0.4f;
  float h=yb-ya, w=xb-xa;
  ps = floorf(sqrtf((h*w)*scale));
  float oy=ya+h*0.5f, ox=xa+w*0.5f;
  float ymp=fmaxf(oy-ps*0.5f,0.f), xmp=fmaxf(ox-ps*0.5f,0.f);
  if (ymp+ps>(float)IMH) ymp=(float)IMH-ps;
  if (xmp+ps>(float)IMW) xmp=(float)IMW-ps;
  yi=(int)ymp; xi=(int)xmp; ph=(int)ps;
  vld = (ps>60.f) ? 1 : 0;
}

// paste value at region-relative (rr,cc); expressions verbatim from passing rounds.
__device__ __forceinline__ void analytic3(int rr, int cc, float phf,
    const float* __restrict__ pbg1, const float* __restrict__ patch,
    const unsigned* msk, const float* ab, float v[3])
{
  float sy = ((rr + 0.5f)*128.0f)/phf - 0.5f;
  float sx = ((cc + 0.5f)*128.0f)/phf - 0.5f;
  sy = fminf(fmaxf(sy, 0.f), 127.f);
  sx = fminf(fmaxf(sx, 0.f), 127.f);
  float fy0 = floorf(sy), fx0 = floorf(sx);
  int py0 = (int)fy0, px0 = (int)fx0;
  int py1 = py0 + 1 < 127 ? py0 + 1 : 127;
  int px1 = px0 + 1 < 127 ? px0 + 1 : 127;
  float wy = sy - fy0, wx = sx - fx0;
  int i00 = (py0<<7)+px0, i01 = (py0<<7)+px1, i10 = (py1<<7)+px0, i11 = (py1<<7)+px1;
  bool m00 = (msk[i00>>5] >> (i00&31)) & 1u;
  bool m01 = (msk[i01>>5] >> (i01&31)) & 1u;
  bool m10 = (msk[i10>>5] >> (i10&31)) & 1u;
  bool m11 = (msk[i11>>5] >> (i11&31)) & 1u;
  #pragma unroll
  for (int ch = 0; ch < 3; ++ch) {
    float a = ab[ch], be = ab[3+ch];
    float t00 = m00 ? patch[i00*3+ch]*a + be : pbg1[i00*3+ch];
    float t01 = m01 ? patch[i01*3+ch]*a + be : pbg1[i01*3+ch];
    float t10 = m10 ? patch[i10*3+ch]*a + be : pbg1[i10*3+ch];
    float t11 = m11 ? patch[i11*3+ch]*a + be : pbg1[i11*3+ch];
    v[ch] = (1.f-wy)*((1.f-wx)*t00 + wx*t01) + wy*((1.f-wx)*t10 + wx*t11);
  }
}

// plain crop: box n of image b, crop block blk (512 px of 16384), from src.
__device__ __forceinline__ void crop_plain(
    const float* __restrict__ src, float* __restrict__ ws, int b, int n, int blk,
    float (*s_red)[6])
{
  const int tid = threadIdx.x;
  const int* bi = (const int*)(ws + WS_BOX + (b*NB + n)*8);
  const int yi = bi[2], xi = bi[3], ph = bi[4];
  const float phf = (float)(ph > 1 ? ph : 1);
  float* __restrict__ pbg = ws + WS_PBG + (size_t)(b*NB + n)*PP2*3;
  float sm[3] = {0,0,0}, sq[3] = {0,0,0};
  #pragma unroll
  for (int k = 0; k < 2; ++k) {
    int idx = blk*512 + k*256 + tid;
    int py = idx >> 7, px = idx & 127;
    float ys = ((float)yi + (py + 0.5f)*phf*(1.0f/PPX)) - 0.5f;
    float xs = ((float)xi + (px + 0.5f)*phf*(1.0f/PPX)) - 0.5f;
    ys = fminf(fmaxf(ys, 0.f), (float)(HP-1));
    xs = fminf(fmaxf(xs, 0.f), (float)(WP-1));
    float fy0 = floorf(ys), fx0 = floorf(xs);
    int y0 = (int)fy0, x0 = (int)fx0;
    int y1 = y0 + 1 < HP-1 ? y0 + 1 : HP-1;
    int x1 = x0 + 1 < WP-1 ? x0 + 1 : WP-1;
    float wy = ys - fy0, wx = xs - fx0;
    bool y0i = y0 < IMH, y1i = y1 < IMH, x0i = x0 < IMW, x1i = x1 < IMW;
    const float* r0 = src + (size_t)y0*IMW*3;
    const float* r1 = src + (size_t)y1*IMW*3;
    #pragma unroll
    for (int c = 0; c < 3; ++c) {
      float v00 = (y0i && x0i) ? r0[x0*3+c] : 0.f;
      float v01 = (y0i && x1i) ? r0[x1*3+c] : 0.f;
      float v10 = (y1i && x0i) ? r1[x0*3+c] : 0.f;
      float v11 = (y1i && x1i) ? r1[x1*3+c] : 0.f;
      float v = (1.f-wy)*((1.f-wx)*v00 + wx*v01) + wy*((1.f-wx)*v10 + wx*v11);
      pbg[idx*3+c] = v;
      sm[c] += v; sq[c] += v*v;
    }
  }
  float vals[6] = {sm[0],sm[1],sm[2],sq[0],sq[1],sq[2]};
  #pragma unroll
  for (int off = 32; off; off >>= 1)
    #pragma unroll
    for (int k = 0; k < 6; ++k) vals[k] += __shfl_down(vals[k], off);
  int wid = tid >> 6;
  __syncthreads();
  if ((tid & 63) == 0)
    for (int k = 0; k < 6; ++k) s_red[wid][k] = vals[k];
  __syncthreads();
  if (tid == 0) {
    float* part = ws + WS_PART + (size_t)((b*NB + n)*32 + blk)*6;
    for (int k = 0; k < 6; ++k)
      part[k] = s_red[0][k] + s_red[1][k] + s_red[2][k] + s_red[3][k];
  }
}

// ------------- setup: masks (1536 blks) + sched/patch-stats (1 blk) -------------
__global__ __launch_bounds__(256) void setup_k(
    const float* __restrict__ boxes,
    const float* __restrict__ Wsc, const float* __restrict__ bsc,
    const float* __restrict__ Wg, const float* __restrict__ bgv,
    const float* __restrict__ patch, float* __restrict__ ws)
{
  const int bid = blockIdx.x, tid = threadIdx.x;

  if (bid < NMB) {
    const int bn = bid >> 3, q = bid & 7;
    float scale, ps; int yi, xi, ph, vld;
    box_geom(boxes + bn*4, Wsc, bsc, scale, ps, yi, xi, ph, vld);
    if (q == 0 && tid == 0) {
      float* bst = ws + WS_BOX + bn*8;
      bst[0] = scale;
      bst[1] = ps;
      ((int*)bst)[2] = yi;
      ((int*)bst)[3] = xi;
      ((int*)bst)[4] = ph;
      bst[5] = vld ? 1.f : 0.f;
    }
    float bh = (boxes[bn*4+2]-boxes[bn*4+0])/(float)IMH;
    float bw = (boxes[bn*4+3]-boxes[bn*4+1])/(float)IMW;
    unsigned* mwords = ((unsigned*)ws) + WS_MASK + bn*512;
    float lsum = 0.f;
    const int lane = tid & 63;
    #pragma unroll
    for (int i = 0; i < 8; ++i) {
      int p = q*2048 + i*256 + tid;
      float zz = bh*Wg[p] + bw*Wg[PP2 + p] + bgv[p];
      lsum += 1.0f / (1.0f + expf(-zz));
      unsigned long long m = __ballot(zz > 0.0f);
      if (lane == 0) {
        int base = p >> 5;
        mwords[base]   = (unsigned)(m & 0xffffffffULL);
        mwords[base+1] = (unsigned)(m >> 32);
      }
    }
    #pragma unroll
    for (int off = 32; off; off >>= 1) lsum += __shfl_down(lsum, off);
    __shared__ float s_r[4];
    if ((tid & 63) == 0) s_r[tid >> 6] = lsum;
    __syncthreads();
    if (tid == 0) ws[WS_MSUM + bn*8 + q] = s_r[0] + s_r[1] + s_r[2] + s_r[3];
    return;
  }

  // last block: patch stats + level schedule + member lists
  __shared__ float s_red6[256][6];
  {
    float s0=0,s1=0,s2=0,q0=0,q1=0,q2=0;
    for (int i = tid; i < PP2; i += 256) {
      float a = patch[i*3+0], b = patch[i*3+1], c = patch[i*3+2];
      s0+=a; s1+=b; s2+=c; q0+=a*a; q1+=b*b; q2+=c*c;
    }
    s_red6[tid][0]=s0; s_red6[tid][1]=s1; s_red6[tid][2]=s2;
    s_red6[tid][3]=q0; s_red6[tid][4]=q1; s_red6[tid][5]=q2;
    __syncthreads();
    for (int s = 128; s > 0; s >>= 1) {
      if (tid < s)
        for (int k=0;k<6;++k) s_red6[tid][k] += s_red6[tid+s][k];
      __syncthreads();
    }
    if (tid == 0) {
      for (int c=0;c<3;++c) {
        float mu  = s_red6[0][c]   * (1.0f/PP2);
        float var = s_red6[0][3+c] * (1.0f/PP2) - mu*mu;
        float sd  = sqrtf(fmaxf(var, 0.f)) + 1e-6f;
        ws[c] = mu; ws[3+c] = sd;
      }
    }
  }
  __syncthreads();
  __shared__ int g_yi[NI*NB], g_xi[NI*NB], g_ph[NI*NB], g_vl[NI*NB];
  if (tid < NI*NB) {
    float scale, ps; int yi, xi, ph, vld;
    box_geom(boxes + tid*4, Wsc, bsc, scale, ps, yi, xi, ph, vld);
    g_yi[tid]=yi; g_xi[tid]=xi; g_ph[tid]=ph; g_vl[tid]=vld;
  }
  __syncthreads();
  if (tid < NI) {
    unsigned* sch = ((unsigned*)ws) + WS_SCH + tid*32;
    unsigned* lst = ((unsigned*)ws) + WS_LIST + tid*(MAXG*NB);
    int lv[NB];
    int cnt[MAXG];
    for (int L = 0; L < MAXG; ++L) cnt[L] = 0;
    for (int n = 0; n < NB; ++n) {
      int idx = tid*NB + n;
      if (!g_vl[idx]) { lv[n] = -1; sch[n] = 255u; continue; }
      int y0 = g_yi[idx]-2, y1 = g_yi[idx]+g_ph[idx]+3;
      int x0 = g_xi[idx]-2, x1 = g_xi[idx]+g_ph[idx]+3;
      int L = 0;
      for (int m = 0; m < n; ++m) {
        if (lv[m] < 0) continue;
        int mi = tid*NB + m;
        int my0 = g_yi[mi]-2, my1 = g_yi[mi]+g_ph[mi]+3;
        int mx0 = g_xi[mi]-2, mx1 = g_xi[mi]+g_ph[mi]+3;
        if (y0 < my1 && my0 < y1 && x0 < mx1 && mx0 < x1)
          L = max(L, lv[m] + 1);
      }
      lv[n] = L;
      sch[n] = (unsigned)L;
      if (L < MAXG) lst[L*NB + cnt[L]++] = (unsigned)n;
    }
    for (int L = 0; L < MAXG; ++L) sch[24 + L] = (unsigned)cnt[L];
  }
}

// ------------- first: [copy 2048][crop lvl0 from images, M1 slots][loss 1] -------------
__global__ __launch_bounds__(256) void first_k(
    float* __restrict__ out, const float* __restrict__ images,
    float* __restrict__ ws)
{
  const int bid = blockIdx.x, tid = threadIdx.x;
  if (bid < NCPY) {
    const float4* src4 = (const float4*)images;
    float4* dst4 = (float4*)out;
    const int n4 = NI*IMH*IMW*3/4;
    for (int i = bid*256 + tid; i < n4; i += NCPY*256) dst4[i] = src4[i];
    return;
  }
  if (bid == NCPY + NI*M1*32) {
    if (tid == 0) {
      float total = 0.f;
      for (int b = 0; b < NI; ++b) {
        float sum_s = 0.f, cnt = 0.f, bgl = 0.f;
        for (int n = 0; n < NB; ++n) {
          const float* bst = ws + WS_BOX + (b*NB + n)*8;
          float v = bst[5];
          float msum = 0.f;
          for (int q = 0; q < 8; ++q) msum += ws[WS_MSUM + (b*NB + n)*8 + q];
          sum_s += bst[0]*v; cnt += v; bgl += (msum*(1.0f/PP2))*v;
        }
        float nn = fmaxf(cnt, 1.0f);
        float m = sum_s / nn;
        float var = 0.f;
        for (int n = 0; n < NB; ++n) {
          const float* bst = ws + WS_BOX + (b*NB + n)*8;
          float d = bst[0] - m;
          var += bst[5]*d*d;
        }
        var /= nn;
        total += bgl + m + 0.5f*var;
      }
      out[(size_t)NI*IMH*IMW*3] = total;
    }
    return;
  }
  const int w = bid - NCPY;
  const int b = w / (M1*32);
  const int rem = w - b*(M1*32);
  const int j = rem >> 5, blk = rem & 31;
  __shared__ float s_red[4][6];
  __shared__ int s_cn[NB];
  __shared__ int s_cc;
  const unsigned* sch = ((const unsigned*)ws) + WS_SCH + b*32;
  if (tid == 0) s_cc = (int)sch[24 + 0];
  __syncthreads();
  const int cc = s_cc;
  if (j >= cc) return;
  if (tid < cc) s_cn[tid] = (int)(((const unsigned*)ws) + WS_LIST + b*(MAXG*NB))[tid];
  __syncthreads();
  const float* src = images + (size_t)b*IMH*IMW*3;
  for (int jj = j; jj < cc; jj += M1)
    crop_plain(src, ws, b, s_cn[jj], blk, s_red);
}

// ------------- crop_k: crop level L from out (prev levels materialized) -------------
__global__ __launch_bounds__(256) void crop_k(
    float* __restrict__ out, float* __restrict__ ws, int L, int M)
{
  const int bid = blockIdx.x, tid = threadIdx.x;
  const int b = bid / (M*32);
  const int rem = bid - b*(M*32);
  const int j = rem >> 5, blk = rem & 31;
  __shared__ float s_red[4][6];
  __shared__ int s_cn[NB];
  __shared__ int s_cc;
  const unsigned* sch = ((const unsigned*)ws) + WS_SCH + b*32;
  if (tid == 0) s_cc = (int)sch[24 + L];
  __syncthreads();
  const int cc = s_cc;
  if (j >= cc) return;
  if (tid < cc) s_cn[tid] = (int)(((const unsigned*)ws) + WS_LIST + b*(MAXG*NB))[L*NB + tid];
  __syncthreads();
  const float* src = out + (size_t)b*IMH*IMW*3;
  for (int jj = j; jj < cc; jj += M)
    crop_plain(src, ws, b, s_cn[jj], blk, s_red);
}

// ------------- paste_k: paste level L (stats of level L ready) -------------
__global__ __launch_bounds__(256) void paste_k(
    float* __restrict__ out, const float* __restrict__ patch,
    float* __restrict__ ws, int L, int M)
{
  const int bid = blockIdx.x, tid = threadIdx.x;
  const int b = bid / (M*32);
  const int rem = bid - b*(M*32);
  const int j = rem >> 5, r = rem & 31;
  __shared__ int s_cp;
  __shared__ int s_pn[NB];
  __shared__ float s_ab[6];
  __shared__ unsigned s_mask[512];
  const unsigned* sch = ((const unsigned*)ws) + WS_SCH + b*32;
  if (tid == 0) s_cp = (int)sch[24 + L];
  __syncthreads();
  const int cp = s_cp;
  if (j >= cp) return;
  if (tid < cp) s_pn[tid] = (int)(((const unsigned*)ws) + WS_LIST + b*(MAXG*NB))[L*NB + tid];
  __syncthreads();
  float* __restrict__ img = out + (size_t)b*IMH*IMW*3;

  for (int jj = j; jj < cp; jj += M) {
    const int n = s_pn[jj];
    // alpha/beta from partial stats
    if (tid < 32) {
      const float* part = ws + WS_PART + (size_t)((b*NB + n)*32 + tid)*6;
      float v[6];
      #pragma unroll
      for (int k = 0; k < 6; ++k) v[k] = part[k];
      #pragma unroll
      for (int off = 16; off; off >>= 1)
        #pragma unroll
        for (int k = 0; k < 6; ++k) v[k] += __shfl_down(v[k], off, 32);
      if (tid == 0) {
        #pragma unroll
        for (int c = 0; c < 3; ++c) {
          float mu  = v[c]   * (1.0f/PP2);
          float var = v[3+c] * (1.0f/PP2) - mu*mu;
          float sd  = sqrtf(fmaxf(var, 0.f)) + 1e-6f;
          float alpha = sd / ws[3+c];
          s_ab[c]   = alpha;
          s_ab[3+c] = mu - ws[c]*alpha;
        }
      }
    }
    {
      const unsigned* mwords = ((const unsigned*)ws) + WS_MASK + (b*NB + n)*512;
      s_mask[tid]       = mwords[tid];
      s_mask[tid + 256] = mwords[tid + 256];
    }
    __syncthreads();
    const int* bi = (const int*)(ws + WS_BOX + (b*NB + n)*8);
    const int yi = bi[2], xi = bi[3], ph = bi[4];
    const float phf = (float)(ph > 1 ? ph : 1);
    const float* pbgp = ws + WS_PBG + (size_t)(b*NB + n)*PP2*3;
    const int tot = ph*ph;
    const int chunk = (tot + 31) / 32;
    const int i0 = r*chunk;
    const int i1 = min(tot, i0 + chunk);
    for (int idx = i0 + tid; idx < i1; idx += 256) {
      int rr = (int)((unsigned)idx / (unsigned)ph);
      int cx = idx - rr*ph;
      float v[3];
      analytic3(rr, cx, phf, pbgp, patch, s_mask, s_ab, v);
      float* dst = img + ((size_t)(yi + rr)*IMW + (xi + cx))*3;
      dst[0] = v[0]; dst[1] = v[1]; dst[2] = v[2];
    }
    __syncthreads();
  }
}

// ------------- fallback: serial per-image processing of lvl>=MAXG boxes -------------
__global__ __launch_bounds__(256) void fallback_k(
    float* __restrict__ out, const float* __restrict__ patch, float* __restrict__ ws)
{
  const int b = blockIdx.x, tid = threadIdx.x;
  const unsigned* sch = ((const unsigned*)ws) + WS_SCH + b*32;
  float* __restrict__ img = out + (size_t)b*IMH*IMW*3;
  float* __restrict__ pbg = ws + WS_PBG + (size_t)(b*NB + 0)*PP2*3;
  __shared__ float s_red6[256][6];
  __shared__ float s_ab[6];
  __shared__ unsigned s_mask[512];

  for (int n = 0; n < NB; ++n) {
    unsigned g = sch[n];
    if (g < (unsigned)MAXG || g == 255u) continue;
    const float* bst = ws + WS_BOX + (b*NB + n)*8;
    const int yi = ((const int*)bst)[2];
    const int xi = ((const int*)bst)[3];
    const int ph = ((const int*)bst)[4];
    const float phf = (float)(ph > 1 ? ph : 1);

    float sm[3]={0,0,0}, sq[3]={0,0,0};
    for (int k = 0; k < PP2/256; ++k) {
      int idx = k*256 + tid;
      int py = idx >> 7, px = idx & 127;
      float ys = ((float)yi + (py + 0.5f)*phf*(1.0f/PPX)) - 0.5f;
      float xs = ((float)xi + (px + 0.5f)*phf*(1.0f/PPX)) - 0.5f;
      ys = fminf(fmaxf(ys, 0.f), (float)(HP-1));
      xs = fminf(fmaxf(xs, 0.f), (float)(WP-1));
      float fy0 = floorf(ys), fx0 = floorf(xs);
      int y0 = (int)fy0, x0 = (int)fx0;
      int y1 = y0 + 1 < HP-1 ? y0 + 1 : HP-1;
      int x1 = x0 + 1 < WP-1 ? x0 + 1 : WP-1;
      float wy = ys - fy0, wx = xs - fx0;
      bool y0i = y0 < IMH, y1i = y1 < IMH, x0i = x0 < IMW, x1i = x1 < IMW;
      const float* r0 = img + (size_t)y0*IMW*3;
      const float* r1 = img + (size_t)y1*IMW*3;
      #pragma unroll
      for (int c = 0; c < 3; ++c) {
        float v00 = (y0i && x0i) ? r0[x0*3+c] : 0.f;
        float v01 = (y0i && x1i) ? r0[x1*3+c] : 0.f;
        float v10 = (y1i && x0i) ? r1[x0*3+c] : 0.f;
        float v11 = (y1i && x1i) ? r1[x1*3+c] : 0.f;
        float v = (1.f-wy)*((1.f-wx)*v00 + wx*v01) + wy*((1.f-wx)*v10 + wx*v11);
        pbg[idx*3+c] = v;
        sm[c] += v; sq[c] += v*v;
      }
    }
    s_red6[tid][0]=sm[0]; s_red6[tid][1]=sm[1]; s_red6[tid][2]=sm[2];
    s_red6[tid][3]=sq[0]; s_red6[tid][4]=sq[1]; s_red6[tid][5]=sq[2];
    __syncthreads();
    for (int s2 = 128; s2 > 0; s2 >>= 1) {
      if (tid < s2)
        for (int k=0;k<6;++k) s_red6[tid][k] += s_red6[tid+s2][k];
      __syncthreads();
    }
    if (tid == 0) {
      for (int c=0;c<3;++c) {
        float mu  = s_red6[0][c]   * (1.0f/PP2);
        float var = s_red6[0][3+c] * (1.0f/PP2) - mu*mu;
        float sd  = sqrtf(fmaxf(var, 0.f)) + 1e-6f;
        float alpha = sd / ws[3+c];
        s_ab[c]   = alpha;
        s_ab[3+c] = mu - ws[c]*alpha;
      }
    }
    {
      const unsigned* mwords = ((const unsigned*)ws) + WS_MASK + (b*NB + n)*512;
      s_mask[tid]       = mwords[tid];
      s_mask[tid + 256] = mwords[tid + 256];
    }
    __syncthreads();
    const int tot = ph*ph;
    for (int idx = tid; idx < tot; idx += 256) {
      int rr = (int)((unsigned)idx / (unsigned)ph);
      int cc = idx - rr*ph;
      float v[3];
      analytic3(rr, cc, phf, pbg, patch, s_mask, s_ab, v);
      float* dst = img + ((size_t)(yi + rr)*IMW + (xi + cc))*3;
      dst[0] = v[0]; dst[1] = v[1]; dst[2] = v[2];
    }
    __syncthreads();
  }
}

extern "C" void kernel_launch(void* const* d_in, const int* in_sizes, int n_in,
                              void* d_out, int out_size, void* d_ws, size_t ws_size,
                              hipStream_t stream) {
  const float* boxes  = (const float*)d_in[0];
  const float* images = (const float*)d_in[1];
  const float* patch  = (const float*)d_in[2];
  const float* Wsc    = (const float*)d_in[3];
  const float* bsc    = (const float*)d_in[4];
  const float* Wg     = (const float*)d_in[5];
  const float* bgv    = (const float*)d_in[6];
  float* out = (float*)d_out;
  float* ws  = (float*)d_ws;

  setup_k<<<NMB + 1, 256, 0, stream>>>(boxes, Wsc, bsc, Wg, bgv, patch, ws);
  first_k<<<NCPY + NI*M1*32 + 1, 256, 0, stream>>>(out, images, ws);   // copy || crop lvl0 || loss
  // paste(L) then crop(L+1), all plain (no read-through)
  paste_k<<<NI*12*32, 256, 0, stream>>>(out, patch, ws, 0, 12);
  crop_k <<<NI*8*32, 256, 0, stream>>>(out, ws, 1, 8);
  paste_k<<<NI*8*32, 256, 0, stream>>>(out, patch, ws, 1, 8);
  crop_k <<<NI*4*32, 256, 0, stream>>>(out, ws, 2, 4);
  paste_k<<<NI*4*32, 256, 0, stream>>>(out, patch, ws, 2, 4);
  crop_k <<<NI*2*32, 256, 0, stream>>>(out, ws, 3, 2);
  paste_k<<<NI*2*32, 256, 0, stream>>>(out, patch, ws, 3, 2);
  crop_k <<<NI*2*32, 256, 0, stream>>>(out, ws, 4, 2);
  paste_k<<<NI*2*32, 256, 0, stream>>>(out, patch, ws, 4, 2);
  crop_k <<<NI*2*32, 256, 0, stream>>>(out, ws, 5, 2);
  paste_k<<<NI*2*32, 256, 0, stream>>>(out, patch, ws, 5, 2);
  fallback_k<<<NI, 256, 0, stream>>>(out, patch, ws);
}

// Round 13
// 200.759 us; speedup vs baseline: 1.5044x; 1.0941x over previous
//
#include <hip/hip_runtime.h>

#define PPX  128
#define PP2  16384
#define IMH  896
#define IMW  896
#define NB   24
#define NI   8
#define HP   1152
#define WP   1152
#define MAXG 6              // scheduled levels 0..5; lvl>=MAXG -> fallback
#define NMB  (NI*NB*8)      // 1536 mask blocks
#define NCPY 2048           // copy blocks at FRONT of first_k
#define M1   12             // crop slots in first_k / paste slots in P0

// ws layout (float units):
// [0..5]                      mu_p[3], sd_p[3]
// [8 .. 8+192*8)              per-box structs
// [2048 .. +192*512)          mask bitmaps (uint32)
// [100352 .. +8*32)           schedule: per image lvl[24] + cnt[MAXG] at [24..] (uint32)
// [100608 .. +8*6*24)         member lists [img][lvl][24] (uint32)
// [101760 .. +192*8)          mask-sum partials [box][chunk]
// [103424 .. +8*24*32*6)      partial stats [box][blk][6]
// [140288 .. +8*24*PP2*3)     pbg slot per box (~38 MB)
#define WS_BOX  8
#define WS_MASK 2048
#define WS_SCH  100352
#define WS_LIST 100608
#define WS_MSUM 101760
#define WS_PART 103424
#define WS_PBG  140288

__device__ __forceinline__ void box_geom(const float* __restrict__ bx,
    const float* __restrict__ Wsc, const float* __restrict__ bsc,
    float& scale, float& ps, int& yi, int& xi, int& ph, int& vld)
{
  float ya=bx[0], xa=bx[1], yb=bx[2], xb=bx[3];
  float bh=(yb-ya)/(float)IMH, bw=(xb-xa)/(float)IMW;
  float z = bh*Wsc[0]+bw*Wsc[1]+bsc[0];
  float sig = 1.f/(1.f+expf(-z));
  scale = sig*0.4f;
  float h=yb-ya, w=xb-xa;
  ps = floorf(sqrtf((h*w)*scale));
  float oy=ya+h*0.5f, ox=xa+w*0.5f;
  float ymp=fmaxf(oy-ps*0.5f,0.f), xmp=fmaxf(ox-ps*0.5f,0.f);
  if (ymp+ps>(float)IMH) ymp=(float)IMH-ps;
  if (xmp+ps>(float)IMW) xmp=(float)IMW-ps;
  yi=(int)ymp; xi=(int)xmp; ph=(int)ps;
  vld = (ps>60.f) ? 1 : 0;
}

// paste value at region-relative (rr,cc); expressions verbatim from passing rounds.
__device__ __forceinline__ void analytic3(int rr, int cc, float phf,
    const float* __restrict__ pbg1, const float* __restrict__ patch,
    const unsigned* msk, const float* ab, float v[3])
{
  float sy = ((rr + 0.5f)*128.0f)/phf - 0.5f;
  float sx = ((cc + 0.5f)*128.0f)/phf - 0.5f;
  sy = fminf(fmaxf(sy, 0.f), 127.f);
  sx = fminf(fmaxf(sx, 0.f), 127.f);
  float fy0 = floorf(sy), fx0 = floorf(sx);
  int py0 = (int)fy0, px0 = (int)fx0;
  int py1 = py0 + 1 < 127 ? py0 + 1 : 127;
  int px1 = px0 + 1 < 127 ? px0 + 1 : 127;
  float wy = sy - fy0, wx = sx - fx0;
  int i00 = (py0<<7)+px0, i01 = (py0<<7)+px1, i10 = (py1<<7)+px0, i11 = (py1<<7)+px1;
  bool m00 = (msk[i00>>5] >> (i00&31)) & 1u;
  bool m01 = (msk[i01>>5] >> (i01&31)) & 1u;
  bool m10 = (msk[i10>>5] >> (i10&31)) & 1u;
  bool m11 = (msk[i11>>5] >> (i11&31)) & 1u;
  #pragma unroll
  for (int ch = 0; ch < 3; ++ch) {
    float a = ab[ch], be = ab[3+ch];
    float t00 = m00 ? patch[i00*3+ch]*a + be : pbg1[i00*3+ch];
    float t01 = m01 ? patch[i01*3+ch]*a + be : pbg1[i01*3+ch];
    float t10 = m10 ? patch[i10*3+ch]*a + be : pbg1[i10*3+ch];
    float t11 = m11 ? patch[i11*3+ch]*a + be : pbg1[i11*3+ch];
    v[ch] = (1.f-wy)*((1.f-wx)*t00 + wx*t01) + wy*((1.f-wx)*t10 + wx*t11);
  }
}

// plain crop: box n of image b, crop block blk (512 px of 16384), from src.
__device__ __forceinline__ void crop_plain(
    const float* __restrict__ src, float* __restrict__ ws, int b, int n, int blk,
    float (*s_red)[6])
{
  const int tid = threadIdx.x;
  const int* bi = (const int*)(ws + WS_BOX + (b*NB + n)*8);
  const int yi = bi[2], xi = bi[3], ph = bi[4];
  const float phf = (float)(ph > 1 ? ph : 1);
  float* __restrict__ pbg = ws + WS_PBG + (size_t)(b*NB + n)*PP2*3;
  float sm[3] = {0,0,0}, sq[3] = {0,0,0};
  #pragma unroll
  for (int k = 0; k < 2; ++k) {
    int idx = blk*512 + k*256 + tid;
    int py = idx >> 7, px = idx & 127;
    float ys = ((float)yi + (py + 0.5f)*phf*(1.0f/PPX)) - 0.5f;
    float xs = ((float)xi + (px + 0.5f)*phf*(1.0f/PPX)) - 0.5f;
    ys = fminf(fmaxf(ys, 0.f), (float)(HP-1));
    xs = fminf(fmaxf(xs, 0.f), (float)(WP-1));
    float fy0 = floorf(ys), fx0 = floorf(xs);
    int y0 = (int)fy0, x0 = (int)fx0;
    int y1 = y0 + 1 < HP-1 ? y0 + 1 : HP-1;
    int x1 = x0 + 1 < WP-1 ? x0 + 1 : WP-1;
    float wy = ys - fy0, wx = xs - fx0;
    bool y0i = y0 < IMH, y1i = y1 < IMH, x0i = x0 < IMW, x1i = x1 < IMW;
    const float* r0 = src + (size_t)y0*IMW*3;
    const float* r1 = src + (size_t)y1*IMW*3;
    #pragma unroll
    for (int c = 0; c < 3; ++c) {
      float v00 = (y0i && x0i) ? r0[x0*3+c] : 0.f;
      float v01 = (y0i && x1i) ? r0[x1*3+c] : 0.f;
      float v10 = (y1i && x0i) ? r1[x0*3+c] : 0.f;
      float v11 = (y1i && x1i) ? r1[x1*3+c] : 0.f;
      float v = (1.f-wy)*((1.f-wx)*v00 + wx*v01) + wy*((1.f-wx)*v10 + wx*v11);
      pbg[idx*3+c] = v;
      sm[c] += v; sq[c] += v*v;
    }
  }
  float vals[6] = {sm[0],sm[1],sm[2],sq[0],sq[1],sq[2]};
  #pragma unroll
  for (int off = 32; off; off >>= 1)
    #pragma unroll
    for (int k = 0; k < 6; ++k) vals[k] += __shfl_down(vals[k], off);
  int wid = tid >> 6;
  __syncthreads();
  if ((tid & 63) == 0)
    for (int k = 0; k < 6; ++k) s_red[wid][k] = vals[k];
  __syncthreads();
  if (tid == 0) {
    float* part = ws + WS_PART + (size_t)((b*NB + n)*32 + blk)*6;
    for (int k = 0; k < 6; ++k)
      part[k] = s_red[0][k] + s_red[1][k] + s_red[2][k] + s_red[3][k];
  }
}

// ------------- sched_k: blk0 = geometry + structs + schedule; blk1 = patch stats -------------
__global__ __launch_bounds__(256) void sched_k(
    const float* __restrict__ boxes,
    const float* __restrict__ Wsc, const float* __restrict__ bsc,
    const float* __restrict__ patch, float* __restrict__ ws)
{
  const int tid = threadIdx.x;
  if (blockIdx.x == 1) {
    // patch stats
    __shared__ float s_red6[256][6];
    float s0=0,s1=0,s2=0,q0=0,q1=0,q2=0;
    for (int i = tid; i < PP2; i += 256) {
      float a = patch[i*3+0], b = patch[i*3+1], c = patch[i*3+2];
      s0+=a; s1+=b; s2+=c; q0+=a*a; q1+=b*b; q2+=c*c;
    }
    s_red6[tid][0]=s0; s_red6[tid][1]=s1; s_red6[tid][2]=s2;
    s_red6[tid][3]=q0; s_red6[tid][4]=q1; s_red6[tid][5]=q2;
    __syncthreads();
    for (int s = 128; s > 0; s >>= 1) {
      if (tid < s)
        for (int k=0;k<6;++k) s_red6[tid][k] += s_red6[tid+s][k];
      __syncthreads();
    }
    if (tid == 0) {
      for (int c=0;c<3;++c) {
        float mu  = s_red6[0][c]   * (1.0f/PP2);
        float var = s_red6[0][3+c] * (1.0f/PP2) - mu*mu;
        float sd  = sqrtf(fmaxf(var, 0.f)) + 1e-6f;
        ws[c] = mu; ws[3+c] = sd;
      }
    }
    return;
  }
  // block 0: geometry + box structs + level schedule + member lists
  __shared__ int g_yi[NI*NB], g_xi[NI*NB], g_ph[NI*NB], g_vl[NI*NB];
  if (tid < NI*NB) {
    float scale, ps; int yi, xi, ph, vld;
    box_geom(boxes + tid*4, Wsc, bsc, scale, ps, yi, xi, ph, vld);
    g_yi[tid]=yi; g_xi[tid]=xi; g_ph[tid]=ph; g_vl[tid]=vld;
    float* bst = ws + WS_BOX + tid*8;
    bst[0] = scale;
    bst[1] = ps;
    ((int*)bst)[2] = yi;
    ((int*)bst)[3] = xi;
    ((int*)bst)[4] = ph;
    bst[5] = vld ? 1.f : 0.f;
  }
  __syncthreads();
  if (tid < NI) {
    unsigned* sch = ((unsigned*)ws) + WS_SCH + tid*32;
    unsigned* lst = ((unsigned*)ws) + WS_LIST + tid*(MAXG*NB);
    int lv[NB];
    int cnt[MAXG];
    for (int L = 0; L < MAXG; ++L) cnt[L] = 0;
    for (int n = 0; n < NB; ++n) {
      int idx = tid*NB + n;
      if (!g_vl[idx]) { lv[n] = -1; sch[n] = 255u; continue; }
      int y0 = g_yi[idx]-2, y1 = g_yi[idx]+g_ph[idx]+3;
      int x0 = g_xi[idx]-2, x1 = g_xi[idx]+g_ph[idx]+3;
      int L = 0;
      for (int m = 0; m < n; ++m) {
        if (lv[m] < 0) continue;
        int mi = tid*NB + m;
        int my0 = g_yi[mi]-2, my1 = g_yi[mi]+g_ph[mi]+3;
        int mx0 = g_xi[mi]-2, mx1 = g_xi[mi]+g_ph[mi]+3;
        if (y0 < my1 && my0 < y1 && x0 < mx1 && mx0 < x1)
          L = max(L, lv[m] + 1);
      }
      lv[n] = L;
      sch[n] = (unsigned)L;
      if (L < MAXG) lst[L*NB + cnt[L]++] = (unsigned)n;
    }
    for (int L = 0; L < MAXG; ++L) sch[24 + L] = (unsigned)cnt[L];
  }
}

// ------------- first: [copy 2048][mask 1536][crop lvl0 from images, M1 slots] -------------
__global__ __launch_bounds__(256) void first_k(
    float* __restrict__ out, const float* __restrict__ images,
    const float* __restrict__ boxes,
    const float* __restrict__ Wg, const float* __restrict__ bgv,
    float* __restrict__ ws)
{
  const int bid = blockIdx.x, tid = threadIdx.x;
  if (bid < NCPY) {
    const float4* src4 = (const float4*)images;
    float4* dst4 = (float4*)out;
    const int n4 = NI*IMH*IMW*3/4;
    for (int i = bid*256 + tid; i < n4; i += NCPY*256) dst4[i] = src4[i];
    return;
  }
  if (bid < NCPY + NMB) {
    // ---- mask chunk q of box bn (sigmoid sign bitmap + partial sums) ----
    const int w = bid - NCPY;
    const int bn = w >> 3, q = w & 7;
    float bh = (boxes[bn*4+2]-boxes[bn*4+0])/(float)IMH;
    float bw = (boxes[bn*4+3]-boxes[bn*4+1])/(float)IMW;
    unsigned* mwords = ((unsigned*)ws) + WS_MASK + bn*512;
    float lsum = 0.f;
    const int lane = tid & 63;
    #pragma unroll
    for (int i = 0; i < 8; ++i) {
      int p = q*2048 + i*256 + tid;
      float zz = bh*Wg[p] + bw*Wg[PP2 + p] + bgv[p];
      lsum += 1.0f / (1.0f + expf(-zz));
      unsigned long long m = __ballot(zz > 0.0f);
      if (lane == 0) {
        int base = p >> 5;
        mwords[base]   = (unsigned)(m & 0xffffffffULL);
        mwords[base+1] = (unsigned)(m >> 32);
      }
    }
    #pragma unroll
    for (int off = 32; off; off >>= 1) lsum += __shfl_down(lsum, off);
    __shared__ float s_r[4];
    if ((tid & 63) == 0) s_r[tid >> 6] = lsum;
    __syncthreads();
    if (tid == 0) ws[WS_MSUM + bn*8 + q] = s_r[0] + s_r[1] + s_r[2] + s_r[3];
    return;
  }
  // ---- crop level 0 from `images` ----
  const int w = bid - NCPY - NMB;
  const int b = w / (M1*32);
  const int rem = w - b*(M1*32);
  const int j = rem >> 5, blk = rem & 31;
  __shared__ float s_red[4][6];
  __shared__ int s_cn[NB];
  __shared__ int s_cc;
  const unsigned* sch = ((const unsigned*)ws) + WS_SCH + b*32;
  if (tid == 0) s_cc = (int)sch[24 + 0];
  __syncthreads();
  const int cc = s_cc;
  if (j >= cc) return;
  if (tid < cc) s_cn[tid] = (int)(((const unsigned*)ws) + WS_LIST + b*(MAXG*NB))[tid];
  __syncthreads();
  const float* src = images + (size_t)b*IMH*IMW*3;
  for (int jj = j; jj < cc; jj += M1)
    crop_plain(src, ws, b, s_cn[jj], blk, s_red);
}

// ------------- crop_k: crop level L from out (prev levels materialized) -------------
__global__ __launch_bounds__(256) void crop_k(
    float* __restrict__ out, float* __restrict__ ws, int L, int M)
{
  const int bid = blockIdx.x, tid = threadIdx.x;
  const int b = bid / (M*32);
  const int rem = bid - b*(M*32);
  const int j = rem >> 5, blk = rem & 31;
  __shared__ float s_red[4][6];
  __shared__ int s_cn[NB];
  __shared__ int s_cc;
  const unsigned* sch = ((const unsigned*)ws) + WS_SCH + b*32;
  if (tid == 0) s_cc = (int)sch[24 + L];
  __syncthreads();
  const int cc = s_cc;
  if (j >= cc) return;
  if (tid < cc) s_cn[tid] = (int)(((const unsigned*)ws) + WS_LIST + b*(MAXG*NB))[L*NB + tid];
  __syncthreads();
  const float* src = out + (size_t)b*IMH*IMW*3;
  for (int jj = j; jj < cc; jj += M)
    crop_plain(src, ws, b, s_cn[jj], blk, s_red);
}

// ------------- paste_k: paste level L; P0 launch has +1 spare block = loss -------------
__global__ __launch_bounds__(256) void paste_k(
    float* __restrict__ out, const float* __restrict__ patch,
    float* __restrict__ ws, int L, int M)
{
  const int bid = blockIdx.x, tid = threadIdx.x;
  if (bid >= NI*M*32) {
    // spare block (only in P0's grid): scalar loss
    if (tid == 0) {
      float total = 0.f;
      for (int b = 0; b < NI; ++b) {
        float sum_s = 0.f, cnt = 0.f, bgl = 0.f;
        for (int n = 0; n < NB; ++n) {
          const float* bst = ws + WS_BOX + (b*NB + n)*8;
          float v = bst[5];
          float msum = 0.f;
          for (int q = 0; q < 8; ++q) msum += ws[WS_MSUM + (b*NB + n)*8 + q];
          sum_s += bst[0]*v; cnt += v; bgl += (msum*(1.0f/PP2))*v;
        }
        float nn = fmaxf(cnt, 1.0f);
        float m = sum_s / nn;
        float var = 0.f;
        for (int n = 0; n < NB; ++n) {
          const float* bst = ws + WS_BOX + (b*NB + n)*8;
          float d = bst[0] - m;
          var += bst[5]*d*d;
        }
        var /= nn;
        total += bgl + m + 0.5f*var;
      }
      out[(size_t)NI*IMH*IMW*3] = total;
    }
    return;
  }
  const int b = bid / (M*32);
  const int rem = bid - b*(M*32);
  const int j = rem >> 5, r = rem & 31;
  __shared__ int s_cp;
  __shared__ int s_pn[NB];
  __shared__ float s_ab[6];
  __shared__ unsigned s_mask[512];
  const unsigned* sch = ((const unsigned*)ws) + WS_SCH + b*32;
  if (tid == 0) s_cp = (int)sch[24 + L];
  __syncthreads();
  const int cp = s_cp;
  if (j >= cp) return;
  if (tid < cp) s_pn[tid] = (int)(((const unsigned*)ws) + WS_LIST + b*(MAXG*NB))[L*NB + tid];
  __syncthreads();
  float* __restrict__ img = out + (size_t)b*IMH*IMW*3;

  for (int jj = j; jj < cp; jj += M) {
    const int n = s_pn[jj];
    if (tid < 32) {
      const float* part = ws + WS_PART + (size_t)((b*NB + n)*32 + tid)*6;
      float v[6];
      #pragma unroll
      for (int k = 0; k < 6; ++k) v[k] = part[k];
      #pragma unroll
      for (int off = 16; off; off >>= 1)
        #pragma unroll
        for (int k = 0; k < 6; ++k) v[k] += __shfl_down(v[k], off, 32);
      if (tid == 0) {
        #pragma unroll
        for (int c = 0; c < 3; ++c) {
          float mu  = v[c]   * (1.0f/PP2);
          float var = v[3+c] * (1.0f/PP2) - mu*mu;
          float sd  = sqrtf(fmaxf(var, 0.f)) + 1e-6f;
          float alpha = sd / ws[3+c];
          s_ab[c]   = alpha;
          s_ab[3+c] = mu - ws[c]*alpha;
        }
      }
    }
    {
      const unsigned* mwords = ((const unsigned*)ws) + WS_MASK + (b*NB + n)*512;
      s_mask[tid]       = mwords[tid];
      s_mask[tid + 256] = mwords[tid + 256];
    }
    __syncthreads();
    const int* bi = (const int*)(ws + WS_BOX + (b*NB + n)*8);
    const int yi = bi[2], xi = bi[3], ph = bi[4];
    const float phf = (float)(ph > 1 ? ph : 1);
    const float* pbgp = ws + WS_PBG + (size_t)(b*NB + n)*PP2*3;
    const int tot = ph*ph;
    const int chunk = (tot + 31) / 32;
    const int i0 = r*chunk;
    const int i1 = min(tot, i0 + chunk);
    for (int idx = i0 + tid; idx < i1; idx += 256) {
      int rr = (int)((unsigned)idx / (unsigned)ph);
      int cx = idx - rr*ph;
      float v[3];
      analytic3(rr, cx, phf, pbgp, patch, s_mask, s_ab, v);
      float* dst = img + ((size_t)(yi + rr)*IMW + (xi + cx))*3;
      dst[0] = v[0]; dst[1] = v[1]; dst[2] = v[2];
    }
    __syncthreads();
  }
}

// ------------- fallback: serial per-image processing of lvl>=MAXG boxes -------------
__global__ __launch_bounds__(256) void fallback_k(
    float* __restrict__ out, const float* __restrict__ patch, float* __restrict__ ws)
{
  const int b = blockIdx.x, tid = threadIdx.x;
  const unsigned* sch = ((const unsigned*)ws) + WS_SCH + b*32;
  float* __restrict__ img = out + (size_t)b*IMH*IMW*3;
  float* __restrict__ pbg = ws + WS_PBG + (size_t)(b*NB + 0)*PP2*3;
  __shared__ float s_red6[256][6];
  __shared__ float s_ab[6];
  __shared__ unsigned s_mask[512];

  for (int n = 0; n < NB; ++n) {
    unsigned g = sch[n];
    if (g < (unsigned)MAXG || g == 255u) continue;
    const float* bst = ws + WS_BOX + (b*NB + n)*8;
    const int yi = ((const int*)bst)[2];
    const int xi = ((const int*)bst)[3];
    const int ph = ((const int*)bst)[4];
    const float phf = (float)(ph > 1 ? ph : 1);

    float sm[3]={0,0,0}, sq[3]={0,0,0};
    for (int k = 0; k < PP2/256; ++k) {
      int idx = k*256 + tid;
      int py = idx >> 7, px = idx & 127;
      float ys = ((float)yi + (py + 0.5f)*phf*(1.0f/PPX)) - 0.5f;
      float xs = ((float)xi + (px + 0.5f)*phf*(1.0f/PPX)) - 0.5f;
      ys = fminf(fmaxf(ys, 0.f), (float)(HP-1));
      xs = fminf(fmaxf(xs, 0.f), (float)(WP-1));
      float fy0 = floorf(ys), fx0 = floorf(xs);
      int y0 = (int)fy0, x0 = (int)fx0;
      int y1 = y0 + 1 < HP-1 ? y0 + 1 : HP-1;
      int x1 = x0 + 1 < WP-1 ? x0 + 1 : WP-1;
      float wy = ys - fy0, wx = xs - fx0;
      bool y0i = y0 < IMH, y1i = y1 < IMH, x0i = x0 < IMW, x1i = x1 < IMW;
      const float* r0 = img + (size_t)y0*IMW*3;
      const float* r1 = img + (size_t)y1*IMW*3;
      #pragma unroll
      for (int c = 0; c < 3; ++c) {
        float v00 = (y0i && x0i) ? r0[x0*3+c] : 0.f;
        float v01 = (y0i && x1i) ? r0[x1*3+c] : 0.f;
        float v10 = (y1i && x0i) ? r1[x0*3+c] : 0.f;
        float v11 = (y1i && x1i) ? r1[x1*3+c] : 0.f;
        float v = (1.f-wy)*((1.f-wx)*v00 + wx*v01) + wy*((1.f-wx)*v10 + wx*v11);
        pbg[idx*3+c] = v;
        sm[c] += v; sq[c] += v*v;
      }
    }
    s_red6[tid][0]=sm[0]; s_red6[tid][1]=sm[1]; s_red6[tid][2]=sm[2];
    s_red6[tid][3]=sq[0]; s_red6[tid][4]=sq[1]; s_red6[tid][5]=sq[2];
    __syncthreads();
    for (int s2 = 128; s2 > 0; s2 >>= 1) {
      if (tid < s2)
        for (int k=0;k<6;++k) s_red6[tid][k] += s_red6[tid+s2][k];
      __syncthreads();
    }
    if (tid == 0) {
      for (int c=0;c<3;++c) {
        float mu  = s_red6[0][c]   * (1.0f/PP2);
        float var = s_red6[0][3+c] * (1.0f/PP2) - mu*mu;
        float sd  = sqrtf(fmaxf(var, 0.f)) + 1e-6f;
        float alpha = sd / ws[3+c];
        s_ab[c]   = alpha;
        s_ab[3+c] = mu - ws[c]*alpha;
      }
    }
    {
      const unsigned* mwords = ((const unsigned*)ws) + WS_MASK + (b*NB + n)*512;
      s_mask[tid]       = mwords[tid];
      s_mask[tid + 256] = mwords[tid + 256];
    }
    __syncthreads();
    const int tot = ph*ph;
    for (int idx = tid; idx < tot; idx += 256) {
      int rr = (int)((unsigned)idx / (unsigned)ph);
      int cc = idx - rr*ph;
      float v[3];
      analytic3(rr, cc, phf, pbg, patch, s_mask, s_ab, v);
      float* dst = img + ((size_t)(yi + rr)*IMW + (xi + cc))*3;
      dst[0] = v[0]; dst[1] = v[1]; dst[2] = v[2];
    }
    __syncthreads();
  }
}

extern "C" void kernel_launch(void* const* d_in, const int* in_sizes, int n_in,
                              void* d_out, int out_size, void* d_ws, size_t ws_size,
                              hipStream_t stream) {
  const float* boxes  = (const float*)d_in[0];
  const float* images = (const float*)d_in[1];
  const float* patch  = (const float*)d_in[2];
  const float* Wsc    = (const float*)d_in[3];
  const float* bsc    = (const float*)d_in[4];
  const float* Wg     = (const float*)d_in[5];
  const float* bgv    = (const float*)d_in[6];
  float* out = (float*)d_out;
  float* ws  = (float*)d_ws;

  sched_k<<<2, 256, 0, stream>>>(boxes, Wsc, bsc, patch, ws);
  first_k<<<NCPY + NMB + NI*M1*32, 256, 0, stream>>>(out, images, boxes, Wg, bgv, ws);
  paste_k<<<NI*M1*32 + 1, 256, 0, stream>>>(out, patch, ws, 0, M1);  // + loss
  crop_k <<<NI*8*32, 256, 0, stream>>>(out, ws, 1, 8);
  paste_k<<<NI*8*32, 256, 0, stream>>>(out, patch, ws, 1, 8);
  crop_k <<<NI*4*32, 256, 0, stream>>>(out, ws, 2, 4);
  paste_k<<<NI*4*32, 256, 0, stream>>>(out, patch, ws, 2, 4);
  crop_k <<<NI*2*32, 256, 0, stream>>>(out, ws, 3, 2);
  paste_k<<<NI*2*32, 256, 0, stream>>>(out, patch, ws, 3, 2);
  crop_k <<<NI*2*32, 256, 0, stream>>>(out, ws, 4, 2);
  paste_k<<<NI*2*32, 256, 0, stream>>>(out, patch, ws, 4, 2);
  crop_k <<<NI*2*32, 256, 0, stream>>>(out, ws, 5, 2);
  paste_k<<<NI*2*32, 256, 0, stream>>>(out, patch, ws, 5, 2);
  fallback_k<<<NI, 256, 0, stream>>>(out, patch, ws);
}